// Round 5
// baseline (390.098 us; speedup 1.0000x reference)
//
#include <hip/hip_runtime.h>
#include <stdint.h>
#include <math.h>

// Problem constants
#define B_ 4
#define H_ 16
#define DM_ 1024
#define NQ_ 1024
#define NK_ 1024
// D_K = D_V = 64

typedef __attribute__((ext_vector_type(4))) float f32x4;
typedef __attribute__((ext_vector_type(4))) int   s32x4;
typedef __attribute__((ext_vector_type(4))) short s16x4;
typedef __attribute__((ext_vector_type(8))) short s16x8;

#define MFMA(a, b, c) __builtin_amdgcn_mfma_f32_16x16x32_bf16(a, b, c, 0, 0, 0)

static __device__ __forceinline__ short f2bf(float f) {
  union { float f; uint32_t u; } v; v.f = f;
  uint32_t r = (v.u + 0x7FFFu + ((v.u >> 16) & 1u)) >> 16;  // RNE
  return (short)(uint16_t)r;
}

static __device__ __forceinline__ float bf2f(short s) {
  union { uint32_t u; float f; } v;
  v.u = ((uint32_t)(uint16_t)s) << 16;
  return v.f;
}

static __device__ __forceinline__ void gload_lds16(const void* g, void* s) {
  __builtin_amdgcn_global_load_lds(
      (const __attribute__((address_space(1))) uint32_t*)g,
      (__attribute__((address_space(3))) uint32_t*)s, 16, 0, 0);
}

// ---------------------------------------------------------------- f32 -> bf16
__global__ void k_cvt(const float* __restrict__ src, short* __restrict__ dst, int n) {
  int i = (blockIdx.x * 256 + threadIdx.x) * 4;
  if (i + 3 < n) {
    f32x4 v = *(const f32x4*)(src + i);
    s16x4 o;
    o.x = f2bf(v.x); o.y = f2bf(v.y); o.z = f2bf(v.z); o.w = f2bf(v.w);
    *(s16x4*)(dst + i) = o;
  }
}

// ---------------------------------------------------------------- GEMM
// C[m][n] = sum_k A[m][k] * Bw[n][k] + bias[n]
// mode 0: out bf16, (B,H,N,64) layout       (Q, K projections)
// mode 1: out bf16, (B,H,64,N) layout       (V projection, transposed)
// mode 2: out f32, plain M x 1024           (output projection)
__global__ __launch_bounds__(256, 2) void k_gemm(
    const short* __restrict__ A, const short* __restrict__ Bw,
    const float* __restrict__ bias, void* __restrict__ outp, int mode) {
  __shared__ short As[128 * 64];
  __shared__ short Bs[128 * 64];
  const int tid = threadIdx.x;
  const int w = tid >> 6, l = tid & 63;
  const int wm = w >> 1, wn = w & 1;
  const int lr = l & 15, lg = l >> 4;
  const int m0 = blockIdx.x * 128, n0 = blockIdx.y * 128;

  f32x4 acc[4][4] = {};

  for (int kt = 0; kt < 16; ++kt) {
    __syncthreads();
#pragma unroll
    for (int q = 0; q < 4; ++q) {
      const int slot = (w * 4 + q) * 64 + l;   // 16B slot index in tile
      const int row = slot >> 3;               // 8 chunks per 128B row
      const int chunk = (slot & 7) ^ (row & 7);
      const size_t goff = (size_t)row * 1024 + (size_t)kt * 64 + chunk * 8;
      gload_lds16(A + (size_t)m0 * 1024 + goff, (char*)As + (w * 4 + q) * 1024);
      gload_lds16(Bw + (size_t)n0 * 1024 + goff, (char*)Bs + (w * 4 + q) * 1024);
    }
    asm volatile("s_waitcnt vmcnt(0)");
    __syncthreads();
#pragma unroll
    for (int ks = 0; ks < 2; ++ks) {
      s16x8 af[4], bfr[4];
#pragma unroll
      for (int mi = 0; mi < 4; ++mi) {
        const int row = wm * 64 + mi * 16 + lr;
        const int chunk = (ks * 4 + lg) ^ (row & 7);
        af[mi] = *(const s16x8*)(As + row * 64 + chunk * 8);
      }
#pragma unroll
      for (int ni = 0; ni < 4; ++ni) {
        const int row = wn * 64 + ni * 16 + lr;
        const int chunk = (ks * 4 + lg) ^ (row & 7);
        bfr[ni] = *(const s16x8*)(Bs + row * 64 + chunk * 8);
      }
#pragma unroll
      for (int mi = 0; mi < 4; ++mi)
#pragma unroll
        for (int ni = 0; ni < 4; ++ni)
          acc[mi][ni] = MFMA(af[mi], bfr[ni], acc[mi][ni]);
    }
  }

  // Epilogue. C frag: row=(lg*4+r), col=lr within each 16x16.
#pragma unroll
  for (int mi = 0; mi < 4; ++mi) {
#pragma unroll
    for (int ni = 0; ni < 4; ++ni) {
      const int gm0 = m0 + wm * 64 + mi * 16 + lg * 4;
      const int gc = n0 + wn * 64 + ni * 16 + lr;
      const float bv = bias[gc];
      if (mode == 2) {
        float* o = (float*)outp;
#pragma unroll
        for (int r = 0; r < 4; ++r)
          o[(size_t)(gm0 + r) * 1024 + gc] = acc[mi][ni][r] + bv;
      } else if (mode == 0) {
        short* o = (short*)outp;
        const int h = gc >> 6, d = gc & 63;
#pragma unroll
        for (int r = 0; r < 4; ++r) {
          const int gm = gm0 + r;
          const int b = gm >> 10, np = gm & 1023;
          o[((size_t)(b * 16 + h) * 1024 + np) * 64 + d] = f2bf(acc[mi][ni][r] + bv);
        }
      } else {  // mode 1: transposed V, pack 4 consecutive n-positions as 8B store
        short* o = (short*)outp;
        const int h = gc >> 6, d = gc & 63;
        const int b = gm0 >> 10, np0 = gm0 & 1023;
        s16x4 pk;
        pk.x = f2bf(acc[mi][ni][0] + bv);
        pk.y = f2bf(acc[mi][ni][1] + bv);
        pk.z = f2bf(acc[mi][ni][2] + bv);
        pk.w = f2bf(acc[mi][ni][3] + bv);
        *(s16x4*)(o + ((size_t)(b * 16 + h) * 64 + d) * 1024 + np0) = pk;
      }
    }
  }
}

// ---------------------------------------------------------------- fused attention (flash split-K)
// Grid: (NQ/64, B*H, 2 splits). 256 threads = 4 waves; wave w owns 16 q-rows.
// R4 lesson: latency-bound (VALUBusy 12%, HBM 36%); the fix is MLP per wave.
// SWAPPED QK^T: s = mfma(K, Q) -> D[row=k][col=q]. Each lane then holds 4
// CONSECUTIVE k for one q-row (q = lane&15), so att_map store / attw load /
// attm load are all 16B/lane vector ops (f32x4 / i32x4): 48 scalar VMEM ->
// 12 vector VMEM per tile, 4x bytes-in-flight per load. Softmax row-reduce:
// 15 in-reg fmax + shfl_xor(16,32). Softmax state is per-lane (q=lane&15);
// corr/inv broadcast to o-fragment rows (q=lg*4+r) via 4 shuffles.
// P -> per-wave LDS as 4x ds_write_b64 (16B-chunk XOR swizzle), PV unchanged.
__global__ __launch_bounds__(256, 4) void k_attn(
    const short* __restrict__ qws, const short* __restrict__ kws,
    const short* __restrict__ vtws,
    const float* __restrict__ attw, const int* __restrict__ attm,
    float* __restrict__ att_map, short* __restrict__ o_part,
    float* __restrict__ mpart, float* __restrict__ lpart) {
  __shared__ short p_lds[4 * 16 * 64];
  const int tid = threadIdx.x;
  const int w = tid >> 6, l = tid & 63;
  const int lr = l & 15, lg = l >> 4;
  const int bh = blockIdx.y;                 // b*16 + h
  const int split = blockIdx.z;
  const int q0 = blockIdx.x * 64 + w * 16;   // this wave's first q row
  char* const pl = (char*)p_lds + w * 2048;  // 16 x 64 bf16, swizzled

  // Q fragments (B-operand: col = lr = q, kk = lg*8 + j), resident all loop
  const short* qb = qws + ((size_t)bh * NQ_ + q0 + lr) * 64 + lg * 8;
  const s16x8 qf0 = *(const s16x8*)(qb);
  const s16x8 qf1 = *(const s16x8*)(qb + 32);

  f32x4 o[4] = {};
  float mrow = -3.0e38f, lrow = 0.0f;   // softmax state for q = q0 + lr

  // row base for att_map/attw/attm: q-row = q0+lr, k offset = kt*64+fn*16+lg*4
  const size_t rowBase = ((size_t)bh * NQ_ + q0 + lr) * (size_t)NK_;

  for (int kt = split * 8; kt < split * 8 + 8; ++kt) {
    // ---- S^T = K Q^T (this wave: 64 k x 16 q); lane holds k = fn*16+lg*4+r
    f32x4 s[4];
    const short* kb0 = kws + ((size_t)bh * NK_ + kt * 64 + lr) * 64 + lg * 8;
#pragma unroll
    for (int fn = 0; fn < 4; ++fn) {
      const short* kb = kb0 + fn * (16 * 64);
      const s16x8 kf0 = *(const s16x8*)(kb);
      const s16x8 kf1 = *(const s16x8*)(kb + 32);
      f32x4 z = {};
      z = MFMA(kf0, qf0, z);
      z = MFMA(kf1, qf1, z);
      s[fn] = z;
    }
    // ---- scale, vectorized att_map store + attw/attm loads (16B/lane)
    float p[4][4];
    const size_t tbase = rowBase + (size_t)kt * 64 + lg * 4;
#pragma unroll
    for (int fn = 0; fn < 4; ++fn) {
      const size_t idx = tbase + fn * 16;
      f32x4 sv;
#pragma unroll
      for (int r = 0; r < 4; ++r) sv[r] = s[fn][r] * 0.125f;
      *(f32x4*)(att_map + idx) = sv;
      const f32x4 wv = *(const f32x4*)(attw + idx);
      const s32x4 mv = *(const s32x4*)(attm + idx);
#pragma unroll
      for (int r = 0; r < 4; ++r)
        p[fn][r] = mv[r] ? sv[r] * wv[r] : -1.0e30f;
    }
    // ---- online softmax: all 16 values of row q=lr live in this lane;
    //      row is split across 4 lanes (lg groups) -> shfl_xor 16,32.
    float t = -3.0e38f;
#pragma unroll
    for (int fn = 0; fn < 4; ++fn)
#pragma unroll
      for (int r = 0; r < 4; ++r) t = fmaxf(t, p[fn][r]);
    t = fmaxf(t, __shfl_xor(t, 16, 64));
    t = fmaxf(t, __shfl_xor(t, 32, 64));
    const float mn = fmaxf(mrow, t);
    const float corr = __expf(mrow - mn);
    mrow = mn;
    float rs = 0.0f;
#pragma unroll
    for (int fn = 0; fn < 4; ++fn)
#pragma unroll
      for (int r = 0; r < 4; ++r) {
        const float e = __expf(p[fn][r] - mn);
        p[fn][r] = e;
        rs += e;
      }
    rs += __shfl_xor(rs, 16, 64);
    rs += __shfl_xor(rs, 32, 64);
    lrow = lrow * corr + rs;
    // ---- rescale o: o rows are q = lg*4 + r -> broadcast corr by q
#pragma unroll
    for (int r = 0; r < 4; ++r) {
      const float cr = __shfl(corr, lg * 4 + r, 64);
      o[0][r] *= cr; o[1][r] *= cr; o[2][r] *= cr; o[3][r] *= cr;
    }
    // ---- P -> per-wave LDS: lane holds P[k=fn*16+lg*4+{0..3}][q=lr];
    //      store transposed as [q][k] rows (128B), 8B packs, XOR-swizzled chunks
#pragma unroll
    for (int fn = 0; fn < 4; ++fn) {
      s16x4 pk;
      pk.x = f2bf(p[fn][0]); pk.y = f2bf(p[fn][1]);
      pk.z = f2bf(p[fn][2]); pk.w = f2bf(p[fn][3]);
      const int chunk = (fn * 2 + (lg >> 1)) ^ (lr & 7);
      *(s16x4*)(pl + lr * 128 + chunk * 16 + (lg & 1) * 8) = pk;
    }
    asm volatile("s_waitcnt lgkmcnt(0)" ::: "memory");
    __builtin_amdgcn_sched_barrier(0);
    // ---- PV: o += P @ V  (A = P rows q=lr, B = V^T rows dv=lr)
    const short* vb0 = vtws + ((size_t)bh * 64 + lr) * (size_t)NK_ + (size_t)kt * 64 + lg * 8;
#pragma unroll
    for (int ks = 0; ks < 2; ++ks) {
      const int chunk = (ks * 4 + lg) ^ (lr & 7);
      const s16x8 pa = *(const s16x8*)(pl + lr * 128 + chunk * 16);
#pragma unroll
      for (int g = 0; g < 4; ++g) {
        const s16x8 vf = *(const s16x8*)(vb0 + (size_t)g * 16 * NK_ + ks * 32);
        o[g] = MFMA(pa, vf, o[g]);
      }
    }
  }

  // ---- write unnormalized partial O (bf16) + per-row m,l
  short* op = o_part + (size_t)split * 4194304;  // [split][bh][q][64]
  const int qrow_base = bh * NQ_ + q0 + lg * 4;  // o rows: q = q0 + lg*4 + r
#pragma unroll
  for (int r = 0; r < 4; ++r) {
    const size_t orow = (size_t)(qrow_base + r) * 64 + lr;
#pragma unroll
    for (int g = 0; g < 4; ++g)
      op[orow + g * 16] = f2bf(o[g][r]);
  }
  if (l < 16) {   // lanes 0..15 hold m,l for q = q0 + l -> coalesced store
    mpart[split * 65536 + bh * NQ_ + q0 + l] = mrow;
    lpart[split * 65536 + bh * NQ_ + q0 + l] = lrow;
  }
}

// ---------------------------------------------------------------- split-K merge
__global__ __launch_bounds__(256, 4) void k_merge(
    const short* __restrict__ o_part, const float* __restrict__ mpart,
    const float* __restrict__ lpart, short* __restrict__ aout) {
  const int t = blockIdx.x * 256 + threadIdx.x;
  const int row = t >> 4;        // bh*1024 + q
  const int d0 = (t & 15) * 4;
  const float m1 = mpart[row], m2 = mpart[65536 + row];
  const float l1 = lpart[row], l2 = lpart[65536 + row];
  const float M = fmaxf(m1, m2);
  const float c1 = __expf(m1 - M), c2 = __expf(m2 - M);
  const float inv = 1.0f / (l1 * c1 + l2 * c2);
  const s16x4 a = *(const s16x4*)(o_part + (size_t)row * 64 + d0);
  const s16x4 b = *(const s16x4*)(o_part + 4194304 + (size_t)row * 64 + d0);
  const int bh = row >> 10, q = row & 1023;
  const int bb = bh >> 4, h = bh & 15;
  s16x4 o;
#pragma unroll
  for (int j = 0; j < 4; ++j)
    o[j] = f2bf((bf2f(a[j]) * c1 + bf2f(b[j]) * c2) * inv);
  *(s16x4*)(aout + ((size_t)(bb * 1024 + q) * 1024 + h * 64 + d0)) = o;
}

// ---------------------------------------------------------------- launch
extern "C" void kernel_launch(void* const* d_in, const int* in_sizes, int n_in,
                              void* d_out, int out_size, void* d_ws, size_t ws_size,
                              hipStream_t stream) {
  const float* queries = (const float*)d_in[0];
  const float* keys    = (const float*)d_in[1];
  const float* values  = (const float*)d_in[2];
  const float* attw    = (const float*)d_in[3];
  const int*   attm    = (const int*)d_in[4];
  const float* Wq = (const float*)d_in[5];
  const float* bq = (const float*)d_in[6];
  const float* Wk = (const float*)d_in[7];
  const float* bk = (const float*)d_in[8];
  const float* Wv = (const float*)d_in[9];
  const float* bv = (const float*)d_in[10];
  const float* Wo = (const float*)d_in[11];
  const float* bo = (const float*)d_in[12];

  float* out = (float*)d_out;                              // (4,1024,1024)
  float* att_map = out + (size_t)B_ * NQ_ * DM_;           // (4,16,1024,1024)

  // Workspace layout (shorts). Total ~67 MB.
  short* ws  = (short*)d_ws;
  short* WqB = ws;                   // 1024*1024
  short* WkB = WqB + 1048576;
  short* WvB = WkB + 1048576;
  short* WoB = WvB + 1048576;
  short* Xq  = WoB + 1048576;        // 4096*1024 each
  short* Xk  = Xq + 4194304;
  short* Xv  = Xk + 4194304;
  short* qws = Xv + 4194304;         // (B,H,NQ,64)
  short* kws = qws + 4194304;        // (B,H,NK,64)
  short* vtw = kws + 4194304;        // (B,H,64,NK)
  short* aout = vtw + 4194304;       // (B*NQ, H*64)

  // Xq/Xk/Xv are dead after the projections -> reuse for split-K partials.
  short* o_part = Xq;                // [2][bh][q][64] bf16 (Xq + Xk regions)
  float* mpart  = (float*)Xv;        // [2][65536] f32
  float* lpart  = mpart + 131072;    // [2][65536] f32

  k_cvt<<<4096, 256, 0, stream>>>(queries, Xq, 4194304);
  k_cvt<<<4096, 256, 0, stream>>>(keys, Xk, 4194304);
  k_cvt<<<4096, 256, 0, stream>>>(values, Xv, 4194304);
  k_cvt<<<1024, 256, 0, stream>>>(Wq, WqB, 1048576);
  k_cvt<<<1024, 256, 0, stream>>>(Wk, WkB, 1048576);
  k_cvt<<<1024, 256, 0, stream>>>(Wv, WvB, 1048576);
  k_cvt<<<1024, 256, 0, stream>>>(Wo, WoB, 1048576);

  dim3 gg(32, 8);
  k_gemm<<<gg, 256, 0, stream>>>(Xq, WqB, bq, qws, 0);
  k_gemm<<<gg, 256, 0, stream>>>(Xk, WkB, bk, kws, 0);
  k_gemm<<<gg, 256, 0, stream>>>(Xv, WvB, bv, vtw, 1);

  dim3 ga(16, 64, 2);
  k_attn<<<ga, 256, 0, stream>>>(qws, kws, vtw, attw, attm, att_map,
                                 o_part, mpart, lpart);
  k_merge<<<4096, 256, 0, stream>>>(o_part, mpart, lpart, aout);

  k_gemm<<<gg, 256, 0, stream>>>(aout, WoB, bo, out, 2);
}

// Round 6
// 365.213 us; speedup vs baseline: 1.0681x; 1.0681x over previous
//
#include <hip/hip_runtime.h>
#include <stdint.h>
#include <math.h>

// Problem constants
#define B_ 4
#define H_ 16
#define DM_ 1024
#define NQ_ 1024
#define NK_ 1024
// D_K = D_V = 64

typedef __attribute__((ext_vector_type(4))) float f32x4;
typedef __attribute__((ext_vector_type(4))) int   s32x4;
typedef __attribute__((ext_vector_type(4))) short s16x4;
typedef __attribute__((ext_vector_type(8))) short s16x8;

#define MFMA(a, b, c) __builtin_amdgcn_mfma_f32_16x16x32_bf16(a, b, c, 0, 0, 0)

static __device__ __forceinline__ short f2bf(float f) {
  union { float f; uint32_t u; } v; v.f = f;
  uint32_t r = (v.u + 0x7FFFu + ((v.u >> 16) & 1u)) >> 16;  // RNE
  return (short)(uint16_t)r;
}

static __device__ __forceinline__ float bf2f(short s) {
  union { uint32_t u; float f; } v;
  v.u = ((uint32_t)(uint16_t)s) << 16;
  return v.f;
}

static __device__ __forceinline__ void gload_lds16(const void* g, void* s) {
  __builtin_amdgcn_global_load_lds(
      (const __attribute__((address_space(1))) uint32_t*)g,
      (__attribute__((address_space(3))) uint32_t*)s, 16, 0, 0);
}

// ---------------------------------------------------------------- f32 -> bf16
__global__ void k_cvt(const float* __restrict__ src, short* __restrict__ dst, int n) {
  int i = (blockIdx.x * 256 + threadIdx.x) * 4;
  if (i + 3 < n) {
    f32x4 v = *(const f32x4*)(src + i);
    s16x4 o;
    o.x = f2bf(v.x); o.y = f2bf(v.y); o.z = f2bf(v.z); o.w = f2bf(v.w);
    *(s16x4*)(dst + i) = o;
  }
}

// ---------------------------------------------------------------- GEMM
// C[m][n] = sum_k A[m][k] * Bw[n][k] + bias[n]
// mode 0: out bf16, (B,H,N,64) layout       (Q, K projections)
// mode 1: out bf16, (B,H,64,N) layout       (V projection, transposed)
// mode 2: out f32, plain M x 1024           (output projection)
__global__ __launch_bounds__(256, 2) void k_gemm(
    const short* __restrict__ A, const short* __restrict__ Bw,
    const float* __restrict__ bias, void* __restrict__ outp, int mode) {
  __shared__ short As[128 * 64];
  __shared__ short Bs[128 * 64];
  const int tid = threadIdx.x;
  const int w = tid >> 6, l = tid & 63;
  const int wm = w >> 1, wn = w & 1;
  const int lr = l & 15, lg = l >> 4;
  const int m0 = blockIdx.x * 128, n0 = blockIdx.y * 128;

  f32x4 acc[4][4] = {};

  for (int kt = 0; kt < 16; ++kt) {
    __syncthreads();
#pragma unroll
    for (int q = 0; q < 4; ++q) {
      const int slot = (w * 4 + q) * 64 + l;   // 16B slot index in tile
      const int row = slot >> 3;               // 8 chunks per 128B row
      const int chunk = (slot & 7) ^ (row & 7);
      const size_t goff = (size_t)row * 1024 + (size_t)kt * 64 + chunk * 8;
      gload_lds16(A + (size_t)m0 * 1024 + goff, (char*)As + (w * 4 + q) * 1024);
      gload_lds16(Bw + (size_t)n0 * 1024 + goff, (char*)Bs + (w * 4 + q) * 1024);
    }
    asm volatile("s_waitcnt vmcnt(0)");
    __syncthreads();
#pragma unroll
    for (int ks = 0; ks < 2; ++ks) {
      s16x8 af[4], bfr[4];
#pragma unroll
      for (int mi = 0; mi < 4; ++mi) {
        const int row = wm * 64 + mi * 16 + lr;
        const int chunk = (ks * 4 + lg) ^ (row & 7);
        af[mi] = *(const s16x8*)(As + row * 64 + chunk * 8);
      }
#pragma unroll
      for (int ni = 0; ni < 4; ++ni) {
        const int row = wn * 64 + ni * 16 + lr;
        const int chunk = (ks * 4 + lg) ^ (row & 7);
        bfr[ni] = *(const s16x8*)(Bs + row * 64 + chunk * 8);
      }
#pragma unroll
      for (int mi = 0; mi < 4; ++mi)
#pragma unroll
        for (int ni = 0; ni < 4; ++ni)
          acc[mi][ni] = MFMA(af[mi], bfr[ni], acc[mi][ni]);
    }
  }

  // Epilogue. C frag: row=(lg*4+r), col=lr within each 16x16.
#pragma unroll
  for (int mi = 0; mi < 4; ++mi) {
#pragma unroll
    for (int ni = 0; ni < 4; ++ni) {
      const int gm0 = m0 + wm * 64 + mi * 16 + lg * 4;
      const int gc = n0 + wn * 64 + ni * 16 + lr;
      const float bv = bias[gc];
      if (mode == 2) {
        float* o = (float*)outp;
#pragma unroll
        for (int r = 0; r < 4; ++r)
          o[(size_t)(gm0 + r) * 1024 + gc] = acc[mi][ni][r] + bv;
      } else if (mode == 0) {
        short* o = (short*)outp;
        const int h = gc >> 6, d = gc & 63;
#pragma unroll
        for (int r = 0; r < 4; ++r) {
          const int gm = gm0 + r;
          const int b = gm >> 10, np = gm & 1023;
          o[((size_t)(b * 16 + h) * 1024 + np) * 64 + d] = f2bf(acc[mi][ni][r] + bv);
        }
      } else {  // mode 1: transposed V, pack 4 consecutive n-positions as 8B store
        short* o = (short*)outp;
        const int h = gc >> 6, d = gc & 63;
        const int b = gm0 >> 10, np0 = gm0 & 1023;
        s16x4 pk;
        pk.x = f2bf(acc[mi][ni][0] + bv);
        pk.y = f2bf(acc[mi][ni][1] + bv);
        pk.z = f2bf(acc[mi][ni][2] + bv);
        pk.w = f2bf(acc[mi][ni][3] + bv);
        *(s16x4*)(o + ((size_t)(b * 16 + h) * 64 + d) * 1024 + np0) = pk;
      }
    }
  }
}

// ---------------------------------------------------------------- fused attention (flash split-K, pipelined)
// Grid: (NQ/64, B*H, 2 splits). 256 threads = 4 waves; wave w owns 16 q-rows.
// R5 lesson: vectorizing w/mask was NEUTRAL -> latency-bound on per-wave MLP,
// not VMEM issue rate. This round: software pipeline (T14).
//  - wv/mv (attw/attm, the ~900cy HBM stream) double-buffered A/B, prefetched
//    1 tile ahead; kt-loop unrolled x2 for static register indexing.
//  - kf (K frags, ~300cy L2) single-buffer ROTATION: dead after S-MFMAs, so
//    next tile's loads reissue into the same regs and their latency hides
//    under softmax+LDS+PV of the current tile.
// launch_bounds(256,2): peak regs ~130-160; a (256,4) cap of 128 would spill
// (R2 lesson). Let allocator land at ~3 waves/SIMD naturally.
#define LOADK(ktx)                                                            \
  {                                                                           \
    const short* kb0_ = kws + ((size_t)bh * NK_ + (ktx) * 64 + lr) * 64 + lg * 8; \
    _Pragma("unroll")                                                         \
    for (int fn = 0; fn < 4; ++fn) {                                          \
      kf[2 * fn]     = *(const s16x8*)(kb0_ + fn * 1024);                     \
      kf[2 * fn + 1] = *(const s16x8*)(kb0_ + fn * 1024 + 32);                \
    }                                                                         \
  }

#define LOADWM(ktx, WV, MV)                                                   \
  {                                                                           \
    const size_t tb_ = rowBase + (size_t)(ktx) * 64 + lg * 4;                 \
    _Pragma("unroll")                                                         \
    for (int fn = 0; fn < 4; ++fn) {                                          \
      WV[fn] = *(const f32x4*)(attw + tb_ + fn * 16);                         \
      MV[fn] = *(const s32x4*)(attm + tb_ + fn * 16);                         \
    }                                                                         \
  }

#define PROCESS(ktc, WV, MV, PREFETCH)                                        \
  {                                                                           \
    /* S^T = K Q^T: lane holds S[k=fn*16+lg*4+r][q=lr] */                     \
    f32x4 s[4];                                                               \
    _Pragma("unroll")                                                         \
    for (int fn = 0; fn < 4; ++fn) {                                          \
      f32x4 z = {};                                                           \
      z = MFMA(kf[2 * fn], qf0, z);                                           \
      z = MFMA(kf[2 * fn + 1], qf1, z);                                       \
      s[fn] = z;                                                              \
    }                                                                         \
    PREFETCH /* kf dead now: rotate K; issue next wv/mv into other buffer */  \
    float p[4][4];                                                            \
    const size_t tbase_ = rowBase + (size_t)(ktc) * 64 + lg * 4;              \
    _Pragma("unroll")                                                         \
    for (int fn = 0; fn < 4; ++fn) {                                          \
      f32x4 sv;                                                               \
      _Pragma("unroll")                                                       \
      for (int r = 0; r < 4; ++r) sv[r] = s[fn][r] * 0.125f;                  \
      *(f32x4*)(att_map + tbase_ + fn * 16) = sv;                             \
      _Pragma("unroll")                                                       \
      for (int r = 0; r < 4; ++r)                                             \
        p[fn][r] = MV[fn][r] ? sv[r] * WV[fn][r] : -1.0e30f;                  \
    }                                                                         \
    /* online softmax for q = q0+lr (row split over lg groups) */             \
    float t = -3.0e38f;                                                       \
    _Pragma("unroll")                                                         \
    for (int fn = 0; fn < 4; ++fn)                                            \
      _Pragma("unroll")                                                       \
      for (int r = 0; r < 4; ++r) t = fmaxf(t, p[fn][r]);                     \
    t = fmaxf(t, __shfl_xor(t, 16, 64));                                      \
    t = fmaxf(t, __shfl_xor(t, 32, 64));                                      \
    const float mn = fmaxf(mrow, t);                                          \
    const float corr = __expf(mrow - mn);                                     \
    mrow = mn;                                                                \
    float rs = 0.0f;                                                          \
    _Pragma("unroll")                                                         \
    for (int fn = 0; fn < 4; ++fn)                                            \
      _Pragma("unroll")                                                       \
      for (int r = 0; r < 4; ++r) {                                           \
        const float e = __expf(p[fn][r] - mn);                                \
        p[fn][r] = e;                                                         \
        rs += e;                                                              \
      }                                                                       \
    rs += __shfl_xor(rs, 16, 64);                                             \
    rs += __shfl_xor(rs, 32, 64);                                             \
    lrow = lrow * corr + rs;                                                  \
    _Pragma("unroll")                                                         \
    for (int r = 0; r < 4; ++r) {                                             \
      const float cr = __shfl(corr, lg * 4 + r, 64);                          \
      o[0][r] *= cr; o[1][r] *= cr; o[2][r] *= cr; o[3][r] *= cr;             \
    }                                                                         \
    /* P -> per-wave LDS (transpose to A layout), 8B packs, XOR swizzle */    \
    _Pragma("unroll")                                                         \
    for (int fn = 0; fn < 4; ++fn) {                                          \
      s16x4 pk;                                                               \
      pk.x = f2bf(p[fn][0]); pk.y = f2bf(p[fn][1]);                           \
      pk.z = f2bf(p[fn][2]); pk.w = f2bf(p[fn][3]);                           \
      const int chunk = (fn * 2 + (lg >> 1)) ^ (lr & 7);                      \
      *(s16x4*)(pl + lr * 128 + chunk * 16 + (lg & 1) * 8) = pk;              \
    }                                                                         \
    asm volatile("s_waitcnt lgkmcnt(0)" ::: "memory");                        \
    __builtin_amdgcn_sched_barrier(0);                                        \
    /* PV: o += P @ V */                                                      \
    const short* vb0_ = vtws + ((size_t)bh * 64 + lr) * (size_t)NK_ +         \
                        (size_t)(ktc) * 64 + lg * 8;                          \
    _Pragma("unroll")                                                         \
    for (int ks = 0; ks < 2; ++ks) {                                          \
      const int chunk = (ks * 4 + lg) ^ (lr & 7);                             \
      const s16x8 pa = *(const s16x8*)(pl + lr * 128 + chunk * 16);           \
      _Pragma("unroll")                                                       \
      for (int g = 0; g < 4; ++g) {                                           \
        const s16x8 vf = *(const s16x8*)(vb0_ + (size_t)g * 16 * NK_ + ks * 32); \
        o[g] = MFMA(pa, vf, o[g]);                                            \
      }                                                                       \
    }                                                                         \
  }

__global__ __launch_bounds__(256, 2) void k_attn(
    const short* __restrict__ qws, const short* __restrict__ kws,
    const short* __restrict__ vtws,
    const float* __restrict__ attw, const int* __restrict__ attm,
    float* __restrict__ att_map, short* __restrict__ o_part,
    float* __restrict__ mpart, float* __restrict__ lpart) {
  __shared__ short p_lds[4 * 16 * 64];
  const int tid = threadIdx.x;
  const int w = tid >> 6, l = tid & 63;
  const int lr = l & 15, lg = l >> 4;
  const int bh = blockIdx.y;                 // b*16 + h
  const int split = blockIdx.z;
  const int q0 = blockIdx.x * 64 + w * 16;   // this wave's first q row
  char* const pl = (char*)p_lds + w * 2048;  // 16 x 64 bf16, swizzled

  // Q fragments (B-operand: col = lr = q, kk = lg*8 + j), resident all loop
  const short* qb = qws + ((size_t)bh * NQ_ + q0 + lr) * 64 + lg * 8;
  const s16x8 qf0 = *(const s16x8*)(qb);
  const s16x8 qf1 = *(const s16x8*)(qb + 32);

  f32x4 o[4] = {};
  float mrow = -3.0e38f, lrow = 0.0f;   // softmax state for q = q0 + lr

  const size_t rowBase = ((size_t)bh * NQ_ + q0 + lr) * (size_t)NK_;

  const int kt0 = split * 8;
  s16x8 kf[8];
  f32x4 wvA[4], wvB[4];
  s32x4 mvA[4], mvB[4];

  LOADK(kt0);
  LOADWM(kt0, wvA, mvA);

  for (int kt = kt0; kt < kt0 + 8; kt += 2) {
    PROCESS(kt, wvA, mvA,
            { LOADK(kt + 1); LOADWM(kt + 1, wvB, mvB); });
    if (kt + 2 < kt0 + 8) {
      PROCESS(kt + 1, wvB, mvB,
              { LOADK(kt + 2); LOADWM(kt + 2, wvA, mvA); });
    } else {
      PROCESS(kt + 1, wvB, mvB, {});
    }
  }

  // ---- write unnormalized partial O (bf16) + per-row m,l
  short* op = o_part + (size_t)split * 4194304;  // [split][bh][q][64]
  const int qrow_base = bh * NQ_ + q0 + lg * 4;  // o rows: q = q0 + lg*4 + r
#pragma unroll
  for (int r = 0; r < 4; ++r) {
    const size_t orow = (size_t)(qrow_base + r) * 64 + lr;
#pragma unroll
    for (int g = 0; g < 4; ++g)
      op[orow + g * 16] = f2bf(o[g][r]);
  }
  if (l < 16) {   // lanes 0..15 hold m,l for q = q0 + l -> coalesced store
    mpart[split * 65536 + bh * NQ_ + q0 + l] = mrow;
    lpart[split * 65536 + bh * NQ_ + q0 + l] = lrow;
  }
}

// ---------------------------------------------------------------- split-K merge
__global__ __launch_bounds__(256, 4) void k_merge(
    const short* __restrict__ o_part, const float* __restrict__ mpart,
    const float* __restrict__ lpart, short* __restrict__ aout) {
  const int t = blockIdx.x * 256 + threadIdx.x;
  const int row = t >> 4;        // bh*1024 + q
  const int d0 = (t & 15) * 4;
  const float m1 = mpart[row], m2 = mpart[65536 + row];
  const float l1 = lpart[row], l2 = lpart[65536 + row];
  const float M = fmaxf(m1, m2);
  const float c1 = __expf(m1 - M), c2 = __expf(m2 - M);
  const float inv = 1.0f / (l1 * c1 + l2 * c2);
  const s16x4 a = *(const s16x4*)(o_part + (size_t)row * 64 + d0);
  const s16x4 b = *(const s16x4*)(o_part + 4194304 + (size_t)row * 64 + d0);
  const int bh = row >> 10, q = row & 1023;
  const int bb = bh >> 4, h = bh & 15;
  s16x4 o;
#pragma unroll
  for (int j = 0; j < 4; ++j)
    o[j] = f2bf((bf2f(a[j]) * c1 + bf2f(b[j]) * c2) * inv);
  *(s16x4*)(aout + ((size_t)(bb * 1024 + q) * 1024 + h * 64 + d0)) = o;
}

// ---------------------------------------------------------------- launch
extern "C" void kernel_launch(void* const* d_in, const int* in_sizes, int n_in,
                              void* d_out, int out_size, void* d_ws, size_t ws_size,
                              hipStream_t stream) {
  const float* queries = (const float*)d_in[0];
  const float* keys    = (const float*)d_in[1];
  const float* values  = (const float*)d_in[2];
  const float* attw    = (const float*)d_in[3];
  const int*   attm    = (const int*)d_in[4];
  const float* Wq = (const float*)d_in[5];
  const float* bq = (const float*)d_in[6];
  const float* Wk = (const float*)d_in[7];
  const float* bk = (const float*)d_in[8];
  const float* Wv = (const float*)d_in[9];
  const float* bv = (const float*)d_in[10];
  const float* Wo = (const float*)d_in[11];
  const float* bo = (const float*)d_in[12];

  float* out = (float*)d_out;                              // (4,1024,1024)
  float* att_map = out + (size_t)B_ * NQ_ * DM_;           // (4,16,1024,1024)

  // Workspace layout (shorts). Total ~67 MB.
  short* ws  = (short*)d_ws;
  short* WqB = ws;                   // 1024*1024
  short* WkB = WqB + 1048576;
  short* WvB = WkB + 1048576;
  short* WoB = WvB + 1048576;
  short* Xq  = WoB + 1048576;        // 4096*1024 each
  short* Xk  = Xq + 4194304;
  short* Xv  = Xk + 4194304;
  short* qws = Xv + 4194304;         // (B,H,NQ,64)
  short* kws = qws + 4194304;        // (B,H,NK,64)
  short* vtw = kws + 4194304;        // (B,H,64,NK)
  short* aout = vtw + 4194304;       // (B*NQ, H*64)

  // Xq/Xk/Xv are dead after the projections -> reuse for split-K partials.
  short* o_part = Xq;                // [2][bh][q][64] bf16 (Xq + Xk regions)
  float* mpart  = (float*)Xv;        // [2][65536] f32
  float* lpart  = mpart + 131072;    // [2][65536] f32

  k_cvt<<<4096, 256, 0, stream>>>(queries, Xq, 4194304);
  k_cvt<<<4096, 256, 0, stream>>>(keys, Xk, 4194304);
  k_cvt<<<4096, 256, 0, stream>>>(values, Xv, 4194304);
  k_cvt<<<1024, 256, 0, stream>>>(Wq, WqB, 1048576);
  k_cvt<<<1024, 256, 0, stream>>>(Wk, WkB, 1048576);
  k_cvt<<<1024, 256, 0, stream>>>(Wv, WvB, 1048576);
  k_cvt<<<1024, 256, 0, stream>>>(Wo, WoB, 1048576);

  dim3 gg(32, 8);
  k_gemm<<<gg, 256, 0, stream>>>(Xq, WqB, bq, qws, 0);
  k_gemm<<<gg, 256, 0, stream>>>(Xk, WkB, bk, kws, 0);
  k_gemm<<<gg, 256, 0, stream>>>(Xv, WvB, bv, vtw, 1);

  dim3 ga(16, 64, 2);
  k_attn<<<ga, 256, 0, stream>>>(qws, kws, vtw, attw, attm, att_map,
                                 o_part, mpart, lpart);
  k_merge<<<4096, 256, 0, stream>>>(o_part, mpart, lpart, aout);

  k_gemm<<<gg, 256, 0, stream>>>(aout, WoB, bo, out, 2);
}